// Round 7
// baseline (115.661 us; speedup 1.0000x reference)
//
#include <hip/hip_runtime.h>
#include <hip/hip_bf16.h>

// UncompressTransformLayer: scatter compressed strict-upper-triangular vector
// (row-major triu order, k=1) into a dense [n,n] fp32 matrix, zeros elsewhere.
// n = 8192, m = n*(n-1)/2 = 33,550,336.
//
// Memory-bound: 256 MiB write (all of out, every call) + 128 MiB read.
// Floor ~ 402 MB / 6.3 TB/s ~ 64 us.
// R1: scalar reads, plain stores            -> 100 us (4.0 TB/s)
// R2: nt stores + 8-wide units              -> 116 us (regressed; reverted)
// R3: aligned f32x4-pair + funnel select    ->  93 us (4.3 TB/s)
// R4: 64B/thread chunks + unaligned reads   -> 131 us (lane stride must be 16B!)
// R5: one unaligned dwordx4 per quad        -> 100 us (misaligned 16B splits)
// R6: two pure-stream kernels (Z then C)    -> 113 us (mixing exonerated)
// R7: R3 + 4-quad ILP batching at GRID-STRIDE spacing (lane stride stays 16B;
//     8 outstanding loads/wave, stores overlap next batch's loads).

#define N_DIM 8192
#define M_TOTAL 33550336u
#define TOTAL_QUADS (8192u * 2048u)          // 16,777,216
#define NTHREADS (2048u * 256u)              // 524,288
#define BATCH 4u
#define OUTER (TOTAL_QUADS / (NTHREADS * BATCH))   // 8

typedef float f32x4 __attribute__((ext_vector_type(4)));

__global__ void __launch_bounds__(256)
uncompress_kernel(const float* __restrict__ comp, float* __restrict__ out) {
    const unsigned tid = blockIdx.x * blockDim.x + threadIdx.x;
    for (unsigned it = 0; it < OUTER; ++it) {
        const unsigned q0 = tid + it * (NTHREADS * BATCH);
        f32x4 v[BATCH], w[BATCH];

        // ---- phase 1: issue all aligned loads for the batch (no waits) ----
#pragma unroll
        for (unsigned b = 0; b < BATCH; ++b) {
            const unsigned q  = q0 + b * NTHREADS;
            const unsigned i  = q >> 11;          // row
            const unsigned j0 = (q & 2047u) << 2; // column of quad
            if (j0 > i) {
                // idx = Offset(i) + (j-i-1); base = Offset(i) - i - 1
                const unsigned off = i * (N_DIM - 1) - ((i * (i - 1u)) >> 1);
                const unsigned c0  = off - i - 1u + j0;
                const unsigned al  = c0 & ~3u;
                v[b] = *reinterpret_cast<const f32x4*>(comp + al);
                const unsigned wi  = (al + 4u <= M_TOTAL - 4u) ? (al + 4u)
                                                               : (M_TOTAL - 4u);
                w[b] = *reinterpret_cast<const f32x4*>(comp + wi);
            }
        }

        // ---- phase 2: funnel-select + store (indices recomputed, VGPR-lean) --
#pragma unroll
        for (unsigned b = 0; b < BATCH; ++b) {
            const unsigned q  = q0 + b * NTHREADS;
            const unsigned i  = q >> 11;
            const unsigned j0 = (q & 2047u) << 2;
            f32x4 v4 = (f32x4)0.f;
            if (j0 > i) {
                const unsigned off = i * (N_DIM - 1) - ((i * (i - 1u)) >> 1);
                const unsigned c0  = off - i - 1u + j0;
                // waves never straddle rows (2048 quads/row, 64 | 2048),
                // so c0&3 is wave-uniform -> scalar branch, exact.
                const unsigned r = __builtin_amdgcn_readfirstlane(c0 & 3u);
                const f32x4 a = v[b], z = w[b];
                switch (r) {
                    case 0: v4 = a; break;
                    case 1: v4 = (f32x4){a.y, a.z, a.w, z.x}; break;
                    case 2: v4 = (f32x4){a.z, a.w, z.x, z.y}; break;
                    default: v4 = (f32x4){a.w, z.x, z.y, z.z}; break;
                }
            } else if (j0 + 3u > i) {
                // diagonal-straddling quad (1 per row): scalar predicated
                const unsigned off  = i * (N_DIM - 1) - ((i * (i - 1u)) >> 1);
                const unsigned base = off - i - 1u;
                v4.x = (j0 + 0u > i) ? comp[base + j0 + 0u] : 0.f;
                v4.y = (j0 + 1u > i) ? comp[base + j0 + 1u] : 0.f;
                v4.z = (j0 + 2u > i) ? comp[base + j0 + 2u] : 0.f;
                v4.w = (j0 + 3u > i) ? comp[base + j0 + 3u] : 0.f;
            }
            *reinterpret_cast<f32x4*>(out + ((size_t)i << 13) + j0) = v4;
        }
    }
}

extern "C" void kernel_launch(void* const* d_in, const int* in_sizes, int n_in,
                              void* d_out, int out_size, void* d_ws, size_t ws_size,
                              hipStream_t stream) {
    const float* comp = (const float*)d_in[0];
    float* out = (float*)d_out;

    // 2048 blocks x 256 threads; each thread: 8 outer iters x 4-quad batch.
    const int block = 256;
    const int grid  = 2048;
    uncompress_kernel<<<grid, block, 0, stream>>>(comp, out);
}

// Round 8
// 92.719 us; speedup vs baseline: 1.2474x; 1.2474x over previous
//
#include <hip/hip_runtime.h>
#include <hip/hip_bf16.h>

// UncompressTransformLayer: scatter compressed strict-upper-triangular vector
// (row-major triu order, k=1) into a dense [n,n] fp32 matrix, zeros elsewhere.
// n = 8192, m = n*(n-1)/2 = 33,550,336.
//
// Memory-bound: 256 MiB write (all of out, every call) + 128 MiB read.
// Floor ~ 402 MB / 6.3 TB/s ~ 64 us.
// R1: scalar reads, plain stores            -> 100 us (4.0 TB/s)
// R2: nt stores + 8-wide units              -> 116 us (reverted)
// R3: aligned f32x4-pair + funnel select    ->  93 us (4.3 TB/s)
// R4: 64B/thread chunks + unaligned reads   -> 131 us (lane stride must be 16B)
// R5: one unaligned dwordx4 per quad        -> 100 us (misaligned 16B splits)
// R6: two pure-stream kernels (Z then C)    -> 113 us (mixing exonerated)
// R7: 4-quad ILP batching (grid-stride)     -> 116 us (batching exonerated)
// R8: ONE WAVE = ONE ROW sequential sweep. Row constants (base, funnel rot,
//     zero/mixed split) hoisted to wave-scalar; hot loop ~6 VALU + 2 ld + 1 st;
//     circular column-phase stagger (i&31) to decorrelate channel access.

#define N_DIM 8192u
#define M_TOTAL 33550336u

typedef float f32x4 __attribute__((ext_vector_type(4)));

// generic iteration (diagonal band / edge): per-element predicated scalar loads
__device__ __forceinline__ void generic_it(const float* __restrict__ comp,
                                           float* __restrict__ orow,
                                           unsigned i, unsigned base,
                                           unsigned it, unsigned lane4) {
    const unsigned j0 = (it << 8) + lane4;
    f32x4 v4;
    v4.x = (j0 + 0u > i) ? comp[base + j0 + 0u] : 0.f;
    v4.y = (j0 + 1u > i) ? comp[base + j0 + 1u] : 0.f;
    v4.z = (j0 + 2u > i) ? comp[base + j0 + 2u] : 0.f;
    v4.w = (j0 + 3u > i) ? comp[base + j0 + 3u] : 0.f;
    *reinterpret_cast<f32x4*>(orow + j0) = v4;
}

// Full row sweep for funnel rotation R = base & 3 (wave-constant).
// it < nz            : full-zero iteration (write-only)
// it == gm (>= nz)   : diagonal-straddling iteration (generic path)
// it > gm            : full-upper iteration (aligned pair + compile-time funnel)
template <unsigned R>
__device__ __forceinline__ void row_sweep(const float* __restrict__ comp,
                                          float* __restrict__ orow,
                                          unsigned i, unsigned base,
                                          unsigned nz, unsigned gm,
                                          unsigned ph, unsigned lane4) {
    for (unsigned k = 0; k < 32u; ++k) {
        const unsigned it = (k + ph) & 31u;   // circular phase stagger
        if (it < nz) {
            // below-diagonal: pure zero store, no loads, no waits
            *reinterpret_cast<f32x4*>(orow + (it << 8) + lane4) = (f32x4)0.f;
        } else if (it == gm) {
            generic_it(comp, orow, i, base, it, lane4);
        } else {
            // fully above diagonal. al is 16B-aligned; covers comp[c0-R .. c0+7-R].
            // Hot path only runs when gm+1 <= it <= 31 => i <= 7935, so the
            // p[1] lookahead stays far inside comp (next rows' data).
            const unsigned j0 = (it << 8) + lane4;
            const unsigned al = (base + j0) & ~3u;
            const f32x4* p = reinterpret_cast<const f32x4*>(comp + al);
            const f32x4 v = p[0];
            f32x4 v4;
            if constexpr (R == 0) {
                v4 = v;                        // pure copy: 1 load, 1 store
            } else {
                const f32x4 w = p[1];          // mostly L1/L2 hit (neighbor's v)
                if constexpr (R == 1)      v4 = (f32x4){v.y, v.z, v.w, w.x};
                else if constexpr (R == 2) v4 = (f32x4){v.z, v.w, w.x, w.y};
                else                       v4 = (f32x4){v.w, w.x, w.y, w.z};
            }
            *reinterpret_cast<f32x4*>(orow + j0) = v4;
        }
    }
}

__global__ void __launch_bounds__(256)
uncompress_kernel(const float* __restrict__ comp, float* __restrict__ out) {
    // one wave per row: 2048 blocks x 4 waves = 8192 waves = 8192 rows
    const unsigned widx  = __builtin_amdgcn_readfirstlane(threadIdx.x >> 6);
    const unsigned i     = blockIdx.x * 4u + widx;        // row (wave-scalar)
    const unsigned lane4 = (threadIdx.x & 63u) << 2;      // column within band

    // row constants (wave-scalar):
    //   idx(i,j) = Offset(i) + (j-i-1),  Offset(i) = i*(n-1) - i*(i-1)/2
    //   base = Offset(i) - i - 1  (idx = base + j; u32 wrap for i=0 is exact)
    const unsigned off  = i * (N_DIM - 1u) - ((i * (i - 1u)) >> 1);
    const unsigned base = off - i - 1u;
    const unsigned nz   = (i + 1u) >> 8;   // # full-zero 256-col bands
    const unsigned gm   = i >> 8;          // diagonal band index
    const unsigned ph   = i & 31u;         // start phase for channel decorrelation
    float* orow = out + ((size_t)i << 13);

    switch (base & 3u) {                    // funnel rotation, wave-constant
        case 0:  row_sweep<0>(comp, orow, i, base, nz, gm, ph, lane4); break;
        case 1:  row_sweep<1>(comp, orow, i, base, nz, gm, ph, lane4); break;
        case 2:  row_sweep<2>(comp, orow, i, base, nz, gm, ph, lane4); break;
        default: row_sweep<3>(comp, orow, i, base, nz, gm, ph, lane4); break;
    }
}

extern "C" void kernel_launch(void* const* d_in, const int* in_sizes, int n_in,
                              void* d_out, int out_size, void* d_ws, size_t ws_size,
                              hipStream_t stream) {
    const float* comp = (const float*)d_in[0];
    float* out = (float*)d_out;

    // 2048 blocks x 256 threads = 8192 waves = one per row, single pass.
    const int block = 256;
    const int grid  = 2048;
    uncompress_kernel<<<grid, block, 0, stream>>>(comp, out);
}

// Round 9
// 88.280 us; speedup vs baseline: 1.3102x; 1.0503x over previous
//
#include <hip/hip_runtime.h>
#include <hip/hip_bf16.h>

// UncompressTransformLayer: scatter compressed strict-upper-triangular vector
// (row-major triu order, k=1) into a dense [n,n] fp32 matrix, zeros elsewhere.
// n = 8192, m = n*(n-1)/2 = 33,550,336.
//
// Memory-bound: 256 MiB write (all of out, every call) + 128 MiB read.
// Floor ~ 402 MB / 6.3 TB/s ~ 64 us.
// R1: scalar reads, plain stores            -> 100 us (4.0 TB/s)
// R2: nt stores + 8-wide units              -> 116 us (reverted)
// R3: aligned f32x4-pair + funnel select    ->  93 us (4.3 TB/s)
// R4: 64B/thread chunks + unaligned reads   -> 131 us (lane stride must be 16B)
// R5: one unaligned dwordx4 per quad        -> 100 us (misaligned splits)
// R6: two pure-stream kernels (Z then C)    -> 113 us (mixing exonerated;
//     copy phase alone ~ whole R3 -> zero stores are FREE, loads are the cost)
// R7: 4-quad ILP batching (grid-stride)     -> 116 us (reverted)
// R8: wave-per-row, branchy rolled sweep    -> 92.7 us (locality neutral)
// R9: wave-per-row, THREE straight-line phases (zeros | diagonal | hot) and
//     depth-2 software pipeline in the hot phase (loads k+1 issued before
//     funnel+store of k -> counted vmcnt, 2x loads in flight, no branches).

#define N_DIM 8192u
#define M_TOTAL 33550336u

typedef float f32x4 __attribute__((ext_vector_type(4)));

// diagonal-straddling band: per-element predicated scalar loads (1 band/row)
__device__ __forceinline__ void generic_band(const float* __restrict__ comp,
                                             float* __restrict__ orow,
                                             unsigned i, unsigned base,
                                             unsigned it, unsigned lane4) {
    const unsigned j0 = (it << 8) + lane4;
    f32x4 v4;
    v4.x = (j0 + 0u > i) ? comp[base + j0 + 0u] : 0.f;
    v4.y = (j0 + 1u > i) ? comp[base + j0 + 1u] : 0.f;
    v4.z = (j0 + 2u > i) ? comp[base + j0 + 2u] : 0.f;
    v4.w = (j0 + 3u > i) ? comp[base + j0 + 3u] : 0.f;
    *reinterpret_cast<f32x4*>(orow + j0) = v4;
}

// hot phase: bands [hstart, 32), all strictly above the diagonal.
// Funnel rotation R = base & 3 is wave-constant (template).
// Depth-2 software pipeline: loads for band k+1 issue before funnel+store of k.
template <unsigned R>
__device__ __forceinline__ void hot_phase(const float* __restrict__ comp,
                                          float* __restrict__ orow,
                                          unsigned base, unsigned hstart,
                                          unsigned lane4) {
    unsigned it = hstart;
    if (it >= 32u) return;

    // aligned 16B base address for band it (per-lane), steps 256 floats/band
    const float* p = comp + (((base + (it << 8) + lane4) & ~3u));
    f32x4 v = *reinterpret_cast<const f32x4*>(p);
    f32x4 w;
    if constexpr (R != 0) w = *reinterpret_cast<const f32x4*>(p + 4);

    for (; it + 1u < 32u; ++it) {
        // issue next band's loads first (overlap with current funnel+store)
        const float* pn = p + 256;
        const f32x4 vn = *reinterpret_cast<const f32x4*>(pn);
        f32x4 wn;
        if constexpr (R != 0) wn = *reinterpret_cast<const f32x4*>(pn + 4);

        f32x4 v4;
        if constexpr (R == 0)      v4 = v;
        else if constexpr (R == 1) v4 = (f32x4){v.y, v.z, v.w, w.x};
        else if constexpr (R == 2) v4 = (f32x4){v.z, v.w, w.x, w.y};
        else                       v4 = (f32x4){v.w, w.x, w.y, w.z};
        *reinterpret_cast<f32x4*>(orow + (it << 8) + lane4) = v4;

        v = vn;
        if constexpr (R != 0) w = wn;
        p = pn;
    }

    // epilogue: last band
    f32x4 v4;
    if constexpr (R == 0)      v4 = v;
    else if constexpr (R == 1) v4 = (f32x4){v.y, v.z, v.w, w.x};
    else if constexpr (R == 2) v4 = (f32x4){v.z, v.w, w.x, w.y};
    else                       v4 = (f32x4){v.w, w.x, w.y, w.z};
    *reinterpret_cast<f32x4*>(orow + (it << 8) + lane4) = v4;
}

__global__ void __launch_bounds__(256)
uncompress_kernel(const float* __restrict__ comp, float* __restrict__ out) {
    // one wave per row: 2048 blocks x 4 waves = 8192 waves = 8192 rows
    const unsigned widx  = __builtin_amdgcn_readfirstlane(threadIdx.x >> 6);
    const unsigned i     = blockIdx.x * 4u + widx;        // row (wave-scalar)
    const unsigned lane4 = (threadIdx.x & 63u) << 2;      // 16B lane stride

    // row constants (wave-scalar):
    //   idx(i,j) = Offset(i) + (j-i-1),  Offset(i) = i*(n-1) - i*(i-1)/2
    //   base = Offset(i) - i - 1  (idx = base + j; u32 wrap for i=0 is exact)
    const unsigned off  = i * (N_DIM - 1u) - ((i * (i - 1u)) >> 1);
    const unsigned base = off - i - 1u;
    const unsigned nz   = (i + 1u) >> 8;   // bands fully at/below diagonal
    const unsigned gm   = i >> 8;          // band containing the diagonal
    float* orow = out + ((size_t)i << 13);

    // phase 1: zero bands [0, nz) — pure fire-and-forget stores
    for (unsigned it = 0; it < nz; ++it)
        *reinterpret_cast<f32x4*>(orow + (it << 8) + lane4) = (f32x4)0.f;

    // phase 2: diagonal band (only if not already covered by the zero phase)
    if (gm >= nz)
        generic_band(comp, orow, i, base, gm, lane4);

    // phase 3: hot bands, wave-constant funnel rotation
    const unsigned hstart = (gm >= nz) ? (gm + 1u) : nz;
    switch (base & 3u) {
        case 0:  hot_phase<0>(comp, orow, base, hstart, lane4); break;
        case 1:  hot_phase<1>(comp, orow, base, hstart, lane4); break;
        case 2:  hot_phase<2>(comp, orow, base, hstart, lane4); break;
        default: hot_phase<3>(comp, orow, base, hstart, lane4); break;
    }
}

extern "C" void kernel_launch(void* const* d_in, const int* in_sizes, int n_in,
                              void* d_out, int out_size, void* d_ws, size_t ws_size,
                              hipStream_t stream) {
    const float* comp = (const float*)d_in[0];
    float* out = (float*)d_out;

    // 2048 blocks x 256 threads = 8192 waves = one per row, single pass.
    const int block = 256;
    const int grid  = 2048;
    uncompress_kernel<<<grid, block, 0, stream>>>(comp, out);
}

// Round 10
// 86.530 us; speedup vs baseline: 1.3367x; 1.0202x over previous
//
#include <hip/hip_runtime.h>
#include <hip/hip_bf16.h>

// UncompressTransformLayer: scatter compressed strict-upper-triangular vector
// (row-major triu order, k=1) into a dense [n,n] fp32 matrix, zeros elsewhere.
// n = 8192, m = n*(n-1)/2 = 33,550,336.
//
// Memory-bound: 256 MiB write (all of out, every call) + 128 MiB read.
// Floor ~ 402 MB / 6.3 TB/s ~ 64 us.
// R1: scalar reads, plain stores            -> 100 us (4.0 TB/s)
// R2: nt stores + 8-wide units              -> 116 us (reverted)
// R3: aligned f32x4-pair + funnel select    ->  93 us (4.3 TB/s)
// R4: 64B/thread chunks + unaligned reads   -> 131 us (lane stride must be 16B)
// R5: one unaligned dwordx4 per quad        -> 100 us (misaligned splits)
// R6: two pure-stream kernels (Z then C)    -> 113 us (mixing exonerated)
// R7: 4-quad ILP batching (grid-stride)     -> 116 us (reverted)
// R8: wave-per-row, branchy rolled sweep    -> 92.7 us (locality neutral)
// R9: straight-line phases + depth-2 pipe   -> 88.3 us (4.55 TB/s)
// R10: depth-4 GROUP pipeline (double-buffered named regs, 8 loads in flight,
//      counted-vmcnt slack spans a full group) + first group's loads issued
//      BEFORE the zero phase (zero stores hide the first load latency).

#define N_DIM 8192u

typedef float f32x4 __attribute__((ext_vector_type(4)));

template <unsigned R>
__device__ __forceinline__ f32x4 funnel(f32x4 v, f32x4 w) {
    if constexpr (R == 0)      return v;
    else if constexpr (R == 1) return (f32x4){v.y, v.z, v.w, w.x};
    else if constexpr (R == 2) return (f32x4){v.z, v.w, w.x, w.y};
    else                       return (f32x4){v.w, w.x, w.y, w.z};
}

template <unsigned R>
__device__ __forceinline__ void row_body(const float* __restrict__ comp,
                                         float* __restrict__ orow,
                                         unsigned i, unsigned base,
                                         unsigned nz, unsigned gm,
                                         unsigned lane4) {
    const unsigned hstart = (gm >= nz) ? (gm + 1u) : nz;  // first hot band
    const unsigned nh = 32u - hstart;                     // # hot bands
    const unsigned ng = nh >> 2;                          // groups of 4
    const float* p = comp + ((base + (hstart << 8) + lane4) & ~3u);
    float* ost = orow + (hstart << 8) + lane4;

    // ---- prologue: issue first hot group's loads BEFORE the zero phase ----
    f32x4 v0{}, v1{}, v2{}, v3{}, w0{}, w1{}, w2{}, w3{};
    if (ng) {
        v0 = *(const f32x4*)(p);
        v1 = *(const f32x4*)(p + 256);
        v2 = *(const f32x4*)(p + 512);
        v3 = *(const f32x4*)(p + 768);
        if constexpr (R != 0) {
            w0 = *(const f32x4*)(p + 4);
            w1 = *(const f32x4*)(p + 260);
            w2 = *(const f32x4*)(p + 516);
            w3 = *(const f32x4*)(p + 772);
        }
    }

    // ---- zero phase: fire-and-forget stores (covers first group's latency) --
    for (unsigned it = 0; it < nz; ++it)
        *(f32x4*)(orow + (it << 8) + lane4) = (f32x4)0.f;

    // ---- diagonal band: exact per-element predication (1 band/row) ----
    if (gm >= nz) {
        const unsigned j0 = (gm << 8) + lane4;
        f32x4 d;
        d.x = (j0 + 0u > i) ? comp[base + j0 + 0u] : 0.f;
        d.y = (j0 + 1u > i) ? comp[base + j0 + 1u] : 0.f;
        d.z = (j0 + 2u > i) ? comp[base + j0 + 2u] : 0.f;
        d.w = (j0 + 3u > i) ? comp[base + j0 + 3u] : 0.f;
        *(f32x4*)(orow + j0) = d;
    }

    // ---- hot groups: load group g+1, then funnel+store group g ----
    for (unsigned g = 1; g < ng; ++g) {
        const float* pn = p + 1024;
        f32x4 a0 = *(const f32x4*)(pn);
        f32x4 a1 = *(const f32x4*)(pn + 256);
        f32x4 a2 = *(const f32x4*)(pn + 512);
        f32x4 a3 = *(const f32x4*)(pn + 768);
        f32x4 b0{}, b1{}, b2{}, b3{};
        if constexpr (R != 0) {
            b0 = *(const f32x4*)(pn + 4);
            b1 = *(const f32x4*)(pn + 260);
            b2 = *(const f32x4*)(pn + 516);
            b3 = *(const f32x4*)(pn + 772);
        }
        *(f32x4*)(ost)        = funnel<R>(v0, w0);
        *(f32x4*)(ost + 256)  = funnel<R>(v1, w1);
        *(f32x4*)(ost + 512)  = funnel<R>(v2, w2);
        *(f32x4*)(ost + 768)  = funnel<R>(v3, w3);
        v0 = a0; v1 = a1; v2 = a2; v3 = a3;
        if constexpr (R != 0) { w0 = b0; w1 = b1; w2 = b2; w3 = b3; }
        p = pn; ost += 1024;
    }
    if (ng) {
        *(f32x4*)(ost)        = funnel<R>(v0, w0);
        *(f32x4*)(ost + 256)  = funnel<R>(v1, w1);
        *(f32x4*)(ost + 512)  = funnel<R>(v2, w2);
        *(f32x4*)(ost + 768)  = funnel<R>(v3, w3);
        p += 1024; ost += 1024;
    }

    // ---- remainder hot bands (nh & 3), depth-1 ----
    for (unsigned r2 = 0; r2 < (nh & 3u); ++r2) {
        f32x4 v = *(const f32x4*)(p);
        f32x4 w{};
        if constexpr (R != 0) w = *(const f32x4*)(p + 4);
        *(f32x4*)(ost) = funnel<R>(v, w);
        p += 256; ost += 256;
    }
}

__global__ void __launch_bounds__(256)
uncompress_kernel(const float* __restrict__ comp, float* __restrict__ out) {
    // one wave per row: 2048 blocks x 4 waves = 8192 waves = 8192 rows
    const unsigned widx  = __builtin_amdgcn_readfirstlane(threadIdx.x >> 6);
    const unsigned i     = blockIdx.x * 4u + widx;        // row (wave-scalar)
    const unsigned lane4 = (threadIdx.x & 63u) << 2;      // 16B lane stride

    // row constants (wave-scalar):
    //   idx(i,j) = Offset(i) + (j-i-1),  Offset(i) = i*(n-1) - i*(i-1)/2
    //   base = Offset(i) - i - 1  (idx = base + j; u32 wrap for i=0 is exact)
    const unsigned off  = i * (N_DIM - 1u) - ((i * (i - 1u)) >> 1);
    const unsigned base = off - i - 1u;
    const unsigned nz   = (i + 1u) >> 8;   // bands fully at/below diagonal
    const unsigned gm   = i >> 8;          // band containing the diagonal
    float* orow = out + ((size_t)i << 13);

    switch (base & 3u) {                    // funnel rotation, wave-constant
        case 0:  row_body<0>(comp, orow, i, base, nz, gm, lane4); break;
        case 1:  row_body<1>(comp, orow, i, base, nz, gm, lane4); break;
        case 2:  row_body<2>(comp, orow, i, base, nz, gm, lane4); break;
        default: row_body<3>(comp, orow, i, base, nz, gm, lane4); break;
    }
}

extern "C" void kernel_launch(void* const* d_in, const int* in_sizes, int n_in,
                              void* d_out, int out_size, void* d_ws, size_t ws_size,
                              hipStream_t stream) {
    const float* comp = (const float*)d_in[0];
    float* out = (float*)d_out;

    // 2048 blocks x 256 threads = 8192 waves = one per row, single pass.
    const int block = 256;
    const int grid  = 2048;
    uncompress_kernel<<<grid, block, 0, stream>>>(comp, out);
}

// Round 11
// 58.873 us; speedup vs baseline: 1.9646x; 1.4698x over previous
//
#include <hip/hip_runtime.h>
#include <hip/hip_bf16.h>

// UncompressTransformLayer: scatter compressed strict-upper-triangular vector
// (row-major triu order, k=1) into a dense [n,n] fp32 matrix, zeros elsewhere.
// n = 8192, m = n*(n-1)/2 = 33,550,336.
//
// Memory-bound: 256 MiB write (all of out, every call) + 128 MiB read.
// Floor ~ 402 MB / 6.3 TB/s ~ 64 us.
// R1: scalar reads, plain stores            -> 100 us (4.0 TB/s)
// R2: nt stores + 8-wide units              -> 116 us (CONFOUNDED: stride bug)
// R3: aligned f32x4-pair + funnel select    ->  93 us (4.3 TB/s)
// R4: 64B/thread chunks + unaligned reads   -> 131 us (lane stride must be 16B)
// R5: one unaligned dwordx4 per quad        -> 100 us (misaligned splits)
// R6: two pure-stream kernels (Z then C)    -> 113 us (mixing exonerated)
// R7: 4-quad ILP batching (grid-stride)     -> 116 us (reverted)
// R8: wave-per-row, branchy rolled sweep    -> 92.7 us (locality neutral)
// R9: straight-line phases + depth-2 pipe   -> 88.3 us (4.55 TB/s)
// R10: depth-4 group pipeline + pre-zero-phase prologue loads -> 86.5 us
// R11: R10 + NONTEMPORAL stores (single change). Theory: 268MB write-allocate
//      stream thrashes L2 against the read stream; nt writes stream through.
//      (R2's nt test was confounded by the 32B-stride regression.)

#define N_DIM 8192u

typedef float f32x4 __attribute__((ext_vector_type(4)));

__device__ __forceinline__ void st_nt(float* p, f32x4 v) {
    __builtin_nontemporal_store(v, reinterpret_cast<f32x4*>(p));
}

template <unsigned R>
__device__ __forceinline__ f32x4 funnel(f32x4 v, f32x4 w) {
    if constexpr (R == 0)      return v;
    else if constexpr (R == 1) return (f32x4){v.y, v.z, v.w, w.x};
    else if constexpr (R == 2) return (f32x4){v.z, v.w, w.x, w.y};
    else                       return (f32x4){v.w, w.x, w.y, w.z};
}

template <unsigned R>
__device__ __forceinline__ void row_body(const float* __restrict__ comp,
                                         float* __restrict__ orow,
                                         unsigned i, unsigned base,
                                         unsigned nz, unsigned gm,
                                         unsigned lane4) {
    const unsigned hstart = (gm >= nz) ? (gm + 1u) : nz;  // first hot band
    const unsigned nh = 32u - hstart;                     // # hot bands
    const unsigned ng = nh >> 2;                          // groups of 4
    const float* p = comp + ((base + (hstart << 8) + lane4) & ~3u);
    float* ost = orow + (hstart << 8) + lane4;

    // ---- prologue: issue first hot group's loads BEFORE the zero phase ----
    f32x4 v0{}, v1{}, v2{}, v3{}, w0{}, w1{}, w2{}, w3{};
    if (ng) {
        v0 = *(const f32x4*)(p);
        v1 = *(const f32x4*)(p + 256);
        v2 = *(const f32x4*)(p + 512);
        v3 = *(const f32x4*)(p + 768);
        if constexpr (R != 0) {
            w0 = *(const f32x4*)(p + 4);
            w1 = *(const f32x4*)(p + 260);
            w2 = *(const f32x4*)(p + 516);
            w3 = *(const f32x4*)(p + 772);
        }
    }

    // ---- zero phase: fire-and-forget nt stores (covers first group latency) --
    for (unsigned it = 0; it < nz; ++it)
        st_nt(orow + (it << 8) + lane4, (f32x4)0.f);

    // ---- diagonal band: exact per-element predication (1 band/row) ----
    if (gm >= nz) {
        const unsigned j0 = (gm << 8) + lane4;
        f32x4 d;
        d.x = (j0 + 0u > i) ? comp[base + j0 + 0u] : 0.f;
        d.y = (j0 + 1u > i) ? comp[base + j0 + 1u] : 0.f;
        d.z = (j0 + 2u > i) ? comp[base + j0 + 2u] : 0.f;
        d.w = (j0 + 3u > i) ? comp[base + j0 + 3u] : 0.f;
        st_nt(orow + j0, d);
    }

    // ---- hot groups: load group g+1, then funnel+store group g ----
    for (unsigned g = 1; g < ng; ++g) {
        const float* pn = p + 1024;
        f32x4 a0 = *(const f32x4*)(pn);
        f32x4 a1 = *(const f32x4*)(pn + 256);
        f32x4 a2 = *(const f32x4*)(pn + 512);
        f32x4 a3 = *(const f32x4*)(pn + 768);
        f32x4 b0{}, b1{}, b2{}, b3{};
        if constexpr (R != 0) {
            b0 = *(const f32x4*)(pn + 4);
            b1 = *(const f32x4*)(pn + 260);
            b2 = *(const f32x4*)(pn + 516);
            b3 = *(const f32x4*)(pn + 772);
        }
        st_nt(ost,       funnel<R>(v0, w0));
        st_nt(ost + 256, funnel<R>(v1, w1));
        st_nt(ost + 512, funnel<R>(v2, w2));
        st_nt(ost + 768, funnel<R>(v3, w3));
        v0 = a0; v1 = a1; v2 = a2; v3 = a3;
        if constexpr (R != 0) { w0 = b0; w1 = b1; w2 = b2; w3 = b3; }
        p = pn; ost += 1024;
    }
    if (ng) {
        st_nt(ost,       funnel<R>(v0, w0));
        st_nt(ost + 256, funnel<R>(v1, w1));
        st_nt(ost + 512, funnel<R>(v2, w2));
        st_nt(ost + 768, funnel<R>(v3, w3));
        p += 1024; ost += 1024;
    }

    // ---- remainder hot bands (nh & 3), depth-1 ----
    for (unsigned r2 = 0; r2 < (nh & 3u); ++r2) {
        f32x4 v = *(const f32x4*)(p);
        f32x4 w{};
        if constexpr (R != 0) w = *(const f32x4*)(p + 4);
        st_nt(ost, funnel<R>(v, w));
        p += 256; ost += 256;
    }
}

__global__ void __launch_bounds__(256)
uncompress_kernel(const float* __restrict__ comp, float* __restrict__ out) {
    // one wave per row: 2048 blocks x 4 waves = 8192 waves = 8192 rows
    const unsigned widx  = __builtin_amdgcn_readfirstlane(threadIdx.x >> 6);
    const unsigned i     = blockIdx.x * 4u + widx;        // row (wave-scalar)
    const unsigned lane4 = (threadIdx.x & 63u) << 2;      // 16B lane stride

    // row constants (wave-scalar):
    //   idx(i,j) = Offset(i) + (j-i-1),  Offset(i) = i*(n-1) - i*(i-1)/2
    //   base = Offset(i) - i - 1  (idx = base + j; u32 wrap for i=0 is exact)
    const unsigned off  = i * (N_DIM - 1u) - ((i * (i - 1u)) >> 1);
    const unsigned base = off - i - 1u;
    const unsigned nz   = (i + 1u) >> 8;   // bands fully at/below diagonal
    const unsigned gm   = i >> 8;          // band containing the diagonal
    float* orow = out + ((size_t)i << 13);

    switch (base & 3u) {                    // funnel rotation, wave-constant
        case 0:  row_body<0>(comp, orow, i, base, nz, gm, lane4); break;
        case 1:  row_body<1>(comp, orow, i, base, nz, gm, lane4); break;
        case 2:  row_body<2>(comp, orow, i, base, nz, gm, lane4); break;
        default: row_body<3>(comp, orow, i, base, nz, gm, lane4); break;
    }
}

extern "C" void kernel_launch(void* const* d_in, const int* in_sizes, int n_in,
                              void* d_out, int out_size, void* d_ws, size_t ws_size,
                              hipStream_t stream) {
    const float* comp = (const float*)d_in[0];
    float* out = (float*)d_out;

    // 2048 blocks x 256 threads = 8192 waves = one per row, single pass.
    const int block = 256;
    const int grid  = 2048;
    uncompress_kernel<<<grid, block, 0, stream>>>(comp, out);
}